// Round 1
// baseline (1368.053 us; speedup 1.0000x reference)
//
#include <hip/hip_runtime.h>
#include <hip/hip_bf16.h>

// ---------------- CSR build ----------------

__global__ void hist_kernel(const int* __restrict__ dst, int* __restrict__ deg, int E) {
    int e = blockIdx.x * blockDim.x + threadIdx.x;
    if (e < E) atomicAdd(&deg[dst[e]], 1);
}

__global__ void scan_kernel(const int* __restrict__ deg, int* __restrict__ row_off,
                            int* __restrict__ cursor, int N) {
    __shared__ int sd[1024];
    __shared__ int carry_s;
    int tid = threadIdx.x;
    if (tid == 0) carry_s = 0;
    __syncthreads();
    for (int base = 0; base < N; base += 1024) {
        int i = base + tid;
        int v = (i < N) ? deg[i] : 0;
        sd[tid] = v;
        __syncthreads();
        for (int off = 1; off < 1024; off <<= 1) {
            int t = (tid >= off) ? sd[tid - off] : 0;
            __syncthreads();
            sd[tid] += t;
            __syncthreads();
        }
        int excl = carry_s + sd[tid] - v;   // exclusive prefix
        if (i < N) { row_off[i] = excl; cursor[i] = excl; }
        __syncthreads();
        if (tid == 1023) carry_s += sd[1023];
        __syncthreads();
    }
    if (tid == 0) row_off[N] = carry_s;
}

__global__ void build_csr_kernel(const int* __restrict__ src, const int* __restrict__ dst,
                                 const float* __restrict__ ea, int* __restrict__ cursor,
                                 int* __restrict__ csr_src, float* __restrict__ csr_w, int E) {
    int e = blockIdx.x * blockDim.x + threadIdx.x;
    if (e < E) {
        int d = dst[e];
        int pos = atomicAdd(&cursor[d], 1);
        csr_src[pos] = src[e];
        csr_w[pos] = ea[e];
    }
}

// ---------------- GEMM: H = X @ W + b  (K = 128 fixed) ----------------

template <int DOUT>
__global__ __launch_bounds__(256) void gemm_bias_kernel(
    const float* __restrict__ X, const float* __restrict__ W,
    const float* __restrict__ b, float* __restrict__ H, int N) {
    constexpr int ROWS = 32;
    constexpr int RPT = ROWS * DOUT / 256;   // rows per thread
    __shared__ float xs[ROWS][128];
    int tid = threadIdx.x;
    int row0 = blockIdx.x * ROWS;

    // stage 32x128 x-tile as float4 (coalesced)
    const float4* Xv = reinterpret_cast<const float4*>(X);
#pragma unroll
    for (int j = 0; j < 4; j++) {
        int idx = tid + j * 256;      // float4 index in [0,1024)
        int r = idx >> 5;
        int c4 = idx & 31;
        float4 v = make_float4(0.f, 0.f, 0.f, 0.f);
        int row = row0 + r;
        if (row < N) v = Xv[(size_t)row * 32 + c4];
        *reinterpret_cast<float4*>(&xs[r][c4 * 4]) = v;
    }
    __syncthreads();

    int c = tid % DOUT;
    int rg = tid / DOUT;
    float acc[RPT];
#pragma unroll
    for (int i = 0; i < RPT; i++) acc[i] = 0.f;

#pragma unroll 4
    for (int k = 0; k < 128; k++) {
        float w = W[k * DOUT + c];            // coalesced, L1/L2-hot
#pragma unroll
        for (int i = 0; i < RPT; i++) acc[i] += xs[rg * RPT + i][k] * w;  // LDS broadcast
    }
    float bb = b[c];
#pragma unroll
    for (int i = 0; i < RPT; i++) {
        int row = row0 + rg * RPT + i;
        if (row < N) H[(size_t)row * DOUT + c] = acc[i] + bb;
    }
}

// ---------------- Aggregate: OUT[n] = H[n] + sum_{e: dst=n} H[src_e] * w_e ----------------

template <int D>
__global__ __launch_bounds__(256) void aggregate_kernel(
    const float* __restrict__ H, const int* __restrict__ row_off,
    const int* __restrict__ csr_src, const float* __restrict__ csr_w,
    float* __restrict__ OUT, int N) {
    constexpr int NPB = 256 / D;
    int n = blockIdx.x * NPB + threadIdx.x / D;
    int d = threadIdx.x % D;
    if (n >= N) return;
    float acc = H[(size_t)n * D + d];
    int e1 = row_off[n + 1];
    for (int e = row_off[n]; e < e1; ++e) {
        int s = csr_src[e];       // uniform across the node's threads
        float w = csr_w[e];
        acc += H[(size_t)s * D + d] * w;   // coalesced row gather
    }
    OUT[(size_t)n * D + d] = acc;
}

// ---------------- Pool ----------------

__global__ void count_kernel(const int* __restrict__ batch, int* __restrict__ cnt, int N) {
    int i = blockIdx.x * blockDim.x + threadIdx.x;
    if (i < N) atomicAdd(&cnt[batch[i]], 1);
}

__global__ void pool_kernel(const float* __restrict__ H, const int* __restrict__ batch,
                            float* __restrict__ sums, int N) {
    const int CHUNK = 256;
    int d = threadIdx.x;                  // 0..63
    int n0 = blockIdx.x * CHUNK;
    int n1 = min(n0 + CHUNK, N);
    int cur = batch[n0];
    float run = 0.f;
    for (int n = n0; n < n1; ++n) {
        int b = batch[n];                 // uniform
        float v = H[(size_t)n * 64 + d];
        if (b != cur) { atomicAdd(&sums[cur * 64 + d], run); run = 0.f; cur = b; }
        run += v;
    }
    atomicAdd(&sums[cur * 64 + d], run);
}

__global__ void finalize_kernel(const float* __restrict__ sums, const int* __restrict__ cnt,
                                float* __restrict__ out) {
    int i = blockIdx.x * blockDim.x + threadIdx.x;
    if (i < 1024) {
        float c = (float)max(cnt[i >> 6], 1);
        out[i] = sums[i] / c;
    }
}

// ---------------- launch ----------------

extern "C" void kernel_launch(void* const* d_in, const int* in_sizes, int n_in,
                              void* d_out, int out_size, void* d_ws, size_t ws_size,
                              hipStream_t stream) {
    const float* x   = (const float*)d_in[0];
    const int*   ei  = (const int*)d_in[1];
    const float* ea  = (const float*)d_in[2];
    const int*   bat = (const int*)d_in[3];
    const float* W1  = (const float*)d_in[4];
    const float* b1  = (const float*)d_in[5];
    const float* W2  = (const float*)d_in[6];
    const float* b2  = (const float*)d_in[7];
    const float* W3  = (const float*)d_in[8];
    const float* b3  = (const float*)d_in[9];

    const int N = in_sizes[0] / 128;
    const int E = in_sizes[2];
    const int* src = ei;
    const int* dst = ei + E;

    auto align = [](size_t v) { return (v + 255) & ~(size_t)255; };
    char* p = (char*)d_ws;
    float* H       = (float*)p; p += align((size_t)N * 128 * sizeof(float));
    float* O       = (float*)p; p += align((size_t)N * 128 * sizeof(float));
    int*   deg     = (int*)p;   p += align((size_t)N * sizeof(int));
    int*   row_off = (int*)p;   p += align((size_t)(N + 1) * sizeof(int));
    int*   cursor  = (int*)p;   p += align((size_t)N * sizeof(int));
    int*   csr_src = (int*)p;   p += align((size_t)E * sizeof(int));
    float* csr_w   = (float*)p; p += align((size_t)E * sizeof(float));
    float* sums    = (float*)p; p += align(1024 * sizeof(float));
    int*   cnt     = (int*)p;   p += align(16 * sizeof(int));

    hipMemsetAsync(deg, 0, (size_t)N * sizeof(int), stream);
    hipMemsetAsync(sums, 0, 1024 * sizeof(float), stream);
    hipMemsetAsync(cnt, 0, 16 * sizeof(int), stream);

    int eb = (E + 255) / 256;
    hist_kernel<<<eb, 256, 0, stream>>>(dst, deg, E);
    scan_kernel<<<1, 1024, 0, stream>>>(deg, row_off, cursor, N);
    build_csr_kernel<<<eb, 256, 0, stream>>>(src, dst, ea, cursor, csr_src, csr_w, E);

    int gb = (N + 31) / 32;
    // layer 1
    gemm_bias_kernel<128><<<gb, 256, 0, stream>>>(x, W1, b1, H, N);
    aggregate_kernel<128><<<(N + 1) / 2, 256, 0, stream>>>(H, row_off, csr_src, csr_w, O, N);
    // layer 2
    gemm_bias_kernel<128><<<gb, 256, 0, stream>>>(O, W2, b2, H, N);
    aggregate_kernel<128><<<(N + 1) / 2, 256, 0, stream>>>(H, row_off, csr_src, csr_w, O, N);
    // layer 3 (DOUT = 64)
    gemm_bias_kernel<64><<<gb, 256, 0, stream>>>(O, W3, b3, H, N);
    aggregate_kernel<64><<<(N + 3) / 4, 256, 0, stream>>>(H, row_off, csr_src, csr_w, O, N);

    // pool
    count_kernel<<<(N + 255) / 256, 256, 0, stream>>>(bat, cnt, N);
    pool_kernel<<<(N + 255) / 256, 64, 0, stream>>>(O, bat, sums, N);
    finalize_kernel<<<4, 256, 0, stream>>>(sums, cnt, (float*)d_out);
}

// Round 2
// 721.949 us; speedup vs baseline: 1.8949x; 1.8949x over previous
//
#include <hip/hip_runtime.h>
#include <hip/hip_bf16.h>

// ---------------- CSR build ----------------

__global__ void hist_kernel(const int* __restrict__ dst, int* __restrict__ deg, int E) {
    int e = blockIdx.x * blockDim.x + threadIdx.x;
    if (e < E) atomicAdd(&deg[dst[e]], 1);
}

// two-pass scan: (1) per-block exclusive scan + block sums
__global__ __launch_bounds__(1024) void scan1_kernel(const int* __restrict__ deg,
                                                     int* __restrict__ row_off,
                                                     int* __restrict__ blk_sums, int N) {
    __shared__ int sd[1024];
    int tid = threadIdx.x;
    int i = blockIdx.x * 1024 + tid;
    int v = (i < N) ? deg[i] : 0;
    sd[tid] = v;
    __syncthreads();
    for (int off = 1; off < 1024; off <<= 1) {
        int t = (tid >= off) ? sd[tid - off] : 0;
        __syncthreads();
        sd[tid] += t;
        __syncthreads();
    }
    if (i < N) row_off[i] = sd[tid] - v;   // block-local exclusive
    if (tid == 1023) blk_sums[blockIdx.x] = sd[1023];
}

// (2) scan the block sums (nb <= 128)
__global__ void scan2_kernel(int* __restrict__ blk, int nb) {
    __shared__ int s[128];
    int t = threadIdx.x;
    int v = (t < nb) ? blk[t] : 0;
    s[t] = v;
    __syncthreads();
    for (int off = 1; off < 128; off <<= 1) {
        int u = (t >= off) ? s[t - off] : 0;
        __syncthreads();
        s[t] += u;
        __syncthreads();
    }
    if (t < nb) blk[t] = s[t] - v;         // exclusive block offsets
}

// (3) add block offsets, fill cursor, set row_off[N]=E
__global__ __launch_bounds__(1024) void scan3_kernel(int* __restrict__ row_off,
                                                     const int* __restrict__ blk_sums,
                                                     int* __restrict__ cursor, int N, int E) {
    int i = blockIdx.x * 1024 + threadIdx.x;
    if (i < N) {
        int r = row_off[i] + blk_sums[blockIdx.x];
        row_off[i] = r;
        cursor[i] = r;
    }
    if (i == 0) row_off[N] = E;
}

__global__ void build_csr_kernel(const int* __restrict__ src, const int* __restrict__ dst,
                                 const float* __restrict__ ea, int* __restrict__ cursor,
                                 int* __restrict__ csr_src, float* __restrict__ csr_w, int E) {
    int e = blockIdx.x * blockDim.x + threadIdx.x;
    if (e < E) {
        int d = dst[e];
        int pos = atomicAdd(&cursor[d], 1);
        csr_src[pos] = src[e];
        csr_w[pos] = ea[e];
    }
}

// ---------------- GEMM: H = X @ W + b  (K = 128 fixed) ----------------

template <int DOUT>
__global__ __launch_bounds__(256) void gemm_bias_kernel(
    const float* __restrict__ X, const float* __restrict__ W,
    const float* __restrict__ b, float* __restrict__ H, int N) {
    constexpr int ROWS = 32;
    constexpr int RPT = ROWS * DOUT / 256;   // rows per thread
    __shared__ float xs[ROWS][128];
    int tid = threadIdx.x;
    int row0 = blockIdx.x * ROWS;

    const float4* Xv = reinterpret_cast<const float4*>(X);
#pragma unroll
    for (int j = 0; j < 4; j++) {
        int idx = tid + j * 256;
        int r = idx >> 5;
        int c4 = idx & 31;
        float4 v = make_float4(0.f, 0.f, 0.f, 0.f);
        int row = row0 + r;
        if (row < N) v = Xv[(size_t)row * 32 + c4];
        *reinterpret_cast<float4*>(&xs[r][c4 * 4]) = v;
    }
    __syncthreads();

    int c = tid % DOUT;
    int rg = tid / DOUT;
    float acc[RPT];
#pragma unroll
    for (int i = 0; i < RPT; i++) acc[i] = 0.f;

#pragma unroll 4
    for (int k = 0; k < 128; k++) {
        float w = W[k * DOUT + c];
#pragma unroll
        for (int i = 0; i < RPT; i++) acc[i] += xs[rg * RPT + i][k] * w;
    }
    float bb = b[c];
#pragma unroll
    for (int i = 0; i < RPT; i++) {
        int row = row0 + rg * RPT + i;
        if (row < N) H[(size_t)row * DOUT + c] = acc[i] + bb;
    }
}

// ---------------- Aggregate: OUT[n] = H[n] + sum_{e: dst=n} H[src_e] * w_e ----------------

template <int D>
__global__ __launch_bounds__(256) void aggregate_kernel(
    const float* __restrict__ H, const int* __restrict__ row_off,
    const int* __restrict__ csr_src, const float* __restrict__ csr_w,
    float* __restrict__ OUT, int N) {
    constexpr int NPB = 256 / D;
    int n = blockIdx.x * NPB + threadIdx.x / D;
    int d = threadIdx.x % D;
    if (n >= N) return;
    float acc = H[(size_t)n * D + d];
    int e1 = row_off[n + 1];
    for (int e = row_off[n]; e < e1; ++e) {
        int s = csr_src[e];
        float w = csr_w[e];
        acc += H[(size_t)s * D + d] * w;
    }
    OUT[(size_t)n * D + d] = acc;
}

// ---------------- Pool ----------------

// batch is sorted: counts = boundary differences via binary search (no atomics)
__global__ void counts_kernel(const int* __restrict__ batch, int* __restrict__ cnt, int N) {
    int g = threadIdx.x;
    if (g >= 16) return;
    auto lower_bound = [&](int key) {
        int lo = 0, hi = N;
        while (lo < hi) { int mid = (lo + hi) >> 1; if (batch[mid] < key) lo = mid + 1; else hi = mid; }
        return lo;
    };
    cnt[g] = lower_bound(g + 1) - lower_bound(g);
}

__global__ void pool_kernel(const float* __restrict__ H, const int* __restrict__ batch,
                            float* __restrict__ sums, int N) {
    const int CHUNK = 256;
    int d = threadIdx.x;                  // 0..63
    int n0 = blockIdx.x * CHUNK;
    int n1 = min(n0 + CHUNK, N);
    int cur = batch[n0];
    float run = 0.f;
    for (int n = n0; n < n1; ++n) {
        int b = batch[n];                 // uniform
        float v = H[(size_t)n * 64 + d];
        if (b != cur) { atomicAdd(&sums[cur * 64 + d], run); run = 0.f; cur = b; }
        run += v;
    }
    atomicAdd(&sums[cur * 64 + d], run);
}

__global__ void finalize_kernel(const float* __restrict__ sums, const int* __restrict__ cnt,
                                float* __restrict__ out) {
    int i = blockIdx.x * blockDim.x + threadIdx.x;
    if (i < 1024) {
        float c = (float)max(cnt[i >> 6], 1);
        out[i] = sums[i] / c;
    }
}

// ---------------- launch ----------------

extern "C" void kernel_launch(void* const* d_in, const int* in_sizes, int n_in,
                              void* d_out, int out_size, void* d_ws, size_t ws_size,
                              hipStream_t stream) {
    const float* x   = (const float*)d_in[0];
    const int*   ei  = (const int*)d_in[1];
    const float* ea  = (const float*)d_in[2];
    const int*   bat = (const int*)d_in[3];
    const float* W1  = (const float*)d_in[4];
    const float* b1  = (const float*)d_in[5];
    const float* W2  = (const float*)d_in[6];
    const float* b2  = (const float*)d_in[7];
    const float* W3  = (const float*)d_in[8];
    const float* b3  = (const float*)d_in[9];

    const int N = in_sizes[0] / 128;
    const int E = in_sizes[2];
    const int* src = ei;
    const int* dst = ei + E;

    auto align = [](size_t v) { return (v + 255) & ~(size_t)255; };
    char* p = (char*)d_ws;
    float* H        = (float*)p; p += align((size_t)N * 128 * sizeof(float));
    float* O        = (float*)p; p += align((size_t)N * 128 * sizeof(float));
    int*   deg      = (int*)p;   p += align((size_t)N * sizeof(int));
    int*   row_off  = (int*)p;   p += align((size_t)(N + 1) * sizeof(int));
    int*   cursor   = (int*)p;   p += align((size_t)N * sizeof(int));
    int*   csr_src  = (int*)p;   p += align((size_t)E * sizeof(int));
    float* csr_w    = (float*)p; p += align((size_t)E * sizeof(float));
    int*   blk_sums = (int*)p;   p += align(128 * sizeof(int));
    float* sums     = (float*)p; p += align(1024 * sizeof(float));
    int*   cnt      = (int*)p;   p += align(16 * sizeof(int));

    hipMemsetAsync(deg, 0, (size_t)N * sizeof(int), stream);
    hipMemsetAsync(sums, 0, 1024 * sizeof(float), stream);

    int eb = (E + 255) / 256;
    int nb = (N + 1023) / 1024;
    hist_kernel<<<eb, 256, 0, stream>>>(dst, deg, E);
    scan1_kernel<<<nb, 1024, 0, stream>>>(deg, row_off, blk_sums, N);
    scan2_kernel<<<1, 128, 0, stream>>>(blk_sums, nb);
    scan3_kernel<<<nb, 1024, 0, stream>>>(row_off, blk_sums, cursor, N, E);
    build_csr_kernel<<<eb, 256, 0, stream>>>(src, dst, ea, cursor, csr_src, csr_w, E);

    int gb = (N + 31) / 32;
    // layer 1
    gemm_bias_kernel<128><<<gb, 256, 0, stream>>>(x, W1, b1, H, N);
    aggregate_kernel<128><<<(N + 1) / 2, 256, 0, stream>>>(H, row_off, csr_src, csr_w, O, N);
    // layer 2
    gemm_bias_kernel<128><<<gb, 256, 0, stream>>>(O, W2, b2, H, N);
    aggregate_kernel<128><<<(N + 1) / 2, 256, 0, stream>>>(H, row_off, csr_src, csr_w, O, N);
    // layer 3 (DOUT = 64)
    gemm_bias_kernel<64><<<gb, 256, 0, stream>>>(O, W3, b3, H, N);
    aggregate_kernel<64><<<(N + 3) / 4, 256, 0, stream>>>(H, row_off, csr_src, csr_w, O, N);

    // pool
    counts_kernel<<<1, 64, 0, stream>>>(bat, cnt, N);
    pool_kernel<<<(N + 255) / 256, 64, 0, stream>>>(O, bat, sums, N);
    finalize_kernel<<<4, 256, 0, stream>>>(sums, cnt, (float*)d_out);
}

// Round 3
// 502.790 us; speedup vs baseline: 2.7209x; 1.4359x over previous
//
#include <hip/hip_runtime.h>
#include <hip/hip_bf16.h>

// ---------------- CSR build ----------------

__global__ void hist_kernel(const int* __restrict__ dst, int* __restrict__ deg, int E) {
    int e = blockIdx.x * blockDim.x + threadIdx.x;
    if (e < E) atomicAdd(&deg[dst[e]], 1);
}

// two-pass scan: (1) per-block exclusive scan + block sums
__global__ __launch_bounds__(1024) void scan1_kernel(const int* __restrict__ deg,
                                                     int* __restrict__ row_off,
                                                     int* __restrict__ blk_sums, int N) {
    __shared__ int sd[1024];
    int tid = threadIdx.x;
    int i = blockIdx.x * 1024 + tid;
    int v = (i < N) ? deg[i] : 0;
    sd[tid] = v;
    __syncthreads();
    for (int off = 1; off < 1024; off <<= 1) {
        int t = (tid >= off) ? sd[tid - off] : 0;
        __syncthreads();
        sd[tid] += t;
        __syncthreads();
    }
    if (i < N) row_off[i] = sd[tid] - v;   // block-local exclusive
    if (tid == 1023) blk_sums[blockIdx.x] = sd[1023];
}

// (2) scan the block sums (nb <= 128)
__global__ void scan2_kernel(int* __restrict__ blk, int nb) {
    __shared__ int s[128];
    int t = threadIdx.x;
    int v = (t < nb) ? blk[t] : 0;
    s[t] = v;
    __syncthreads();
    for (int off = 1; off < 128; off <<= 1) {
        int u = (t >= off) ? s[t - off] : 0;
        __syncthreads();
        s[t] += u;
        __syncthreads();
    }
    if (t < nb) blk[t] = s[t] - v;         // exclusive block offsets
}

// (3) add block offsets, fill cursor, set row_off[N]=E
__global__ __launch_bounds__(1024) void scan3_kernel(int* __restrict__ row_off,
                                                     const int* __restrict__ blk_sums,
                                                     int* __restrict__ cursor, int N, int E) {
    int i = blockIdx.x * 1024 + threadIdx.x;
    if (i < N) {
        int r = row_off[i] + blk_sums[blockIdx.x];
        row_off[i] = r;
        cursor[i] = r;
    }
    if (i == 0) row_off[N] = E;
}

// csr[pos] = {src, w-as-int} interleaved -> one 8B uniform load per edge
__global__ void build_csr_kernel(const int* __restrict__ src, const int* __restrict__ dst,
                                 const float* __restrict__ ea, int* __restrict__ cursor,
                                 int2* __restrict__ csr, int E) {
    int e = blockIdx.x * blockDim.x + threadIdx.x;
    if (e < E) {
        int d = dst[e];
        int pos = atomicAdd(&cursor[d], 1);
        csr[pos] = make_int2(src[e], __float_as_int(ea[e]));
    }
}

// ---------------- GEMM: H = X @ W + b  (K = 128 fixed) ----------------

template <int DOUT>
__global__ __launch_bounds__(256) void gemm_bias_kernel(
    const float* __restrict__ X, const float* __restrict__ W,
    const float* __restrict__ b, float* __restrict__ H, int N) {
    constexpr int ROWS = 32;
    constexpr int RPT = ROWS * DOUT / 256;   // rows per thread
    __shared__ float xs[ROWS][128];
    int tid = threadIdx.x;
    int row0 = blockIdx.x * ROWS;

    const float4* Xv = reinterpret_cast<const float4*>(X);
#pragma unroll
    for (int j = 0; j < 4; j++) {
        int idx = tid + j * 256;
        int r = idx >> 5;
        int c4 = idx & 31;
        float4 v = make_float4(0.f, 0.f, 0.f, 0.f);
        int row = row0 + r;
        if (row < N) v = Xv[(size_t)row * 32 + c4];
        *reinterpret_cast<float4*>(&xs[r][c4 * 4]) = v;
    }
    __syncthreads();

    int c = tid % DOUT;
    int rg = tid / DOUT;
    float acc[RPT];
#pragma unroll
    for (int i = 0; i < RPT; i++) acc[i] = 0.f;

#pragma unroll 4
    for (int k = 0; k < 128; k++) {
        float w = W[k * DOUT + c];
#pragma unroll
        for (int i = 0; i < RPT; i++) acc[i] += xs[rg * RPT + i][k] * w;
    }
    float bb = b[c];
#pragma unroll
    for (int i = 0; i < RPT; i++) {
        int row = row0 + rg * RPT + i;
        if (row < N) H[(size_t)row * DOUT + c] = acc[i] + bb;
    }
}

// ---------------- Aggregate: OUT[n] = H[n] + sum_{e: dst=n} H[src_e] * w_e ----------------
// float4 per lane (TPN = D/4 threads per node), 4-way edge unroll for MLP.

template <int D>
__global__ __launch_bounds__(256) void aggregate_kernel(
    const float* __restrict__ H, const int* __restrict__ row_off,
    const int2* __restrict__ csr, float* __restrict__ OUT, int N) {
    constexpr int TPN = D / 4;              // threads per node
    constexpr int NPB = 256 / TPN;          // nodes per block
    int n = blockIdx.x * NPB + threadIdx.x / TPN;
    int d4 = threadIdx.x % TPN;
    if (n >= N) return;
    const float4* Hv = reinterpret_cast<const float4*>(H);
    float4 acc = Hv[(size_t)n * TPN + d4];
    int e = row_off[n];
    int e1 = row_off[n + 1];
    for (; e + 4 <= e1; e += 4) {
        int2 c0 = csr[e], c1 = csr[e + 1], c2 = csr[e + 2], c3 = csr[e + 3];
        float4 v0 = Hv[(size_t)c0.x * TPN + d4];
        float4 v1 = Hv[(size_t)c1.x * TPN + d4];
        float4 v2 = Hv[(size_t)c2.x * TPN + d4];
        float4 v3 = Hv[(size_t)c3.x * TPN + d4];
        float w0 = __int_as_float(c0.y), w1 = __int_as_float(c1.y);
        float w2 = __int_as_float(c2.y), w3 = __int_as_float(c3.y);
        acc.x += v0.x * w0 + v1.x * w1 + v2.x * w2 + v3.x * w3;
        acc.y += v0.y * w0 + v1.y * w1 + v2.y * w2 + v3.y * w3;
        acc.z += v0.z * w0 + v1.z * w1 + v2.z * w2 + v3.z * w3;
        acc.w += v0.w * w0 + v1.w * w1 + v2.w * w2 + v3.w * w3;
    }
    for (; e < e1; ++e) {
        int2 c = csr[e];
        float4 v = Hv[(size_t)c.x * TPN + d4];
        float w = __int_as_float(c.y);
        acc.x += v.x * w; acc.y += v.y * w; acc.z += v.z * w; acc.w += v.w * w;
    }
    reinterpret_cast<float4*>(OUT)[(size_t)n * TPN + d4] = acc;
}

// ---------------- Pool ----------------

// batch is sorted: counts = boundary differences via binary search (no atomics)
__global__ void counts_kernel(const int* __restrict__ batch, int* __restrict__ cnt, int N) {
    int g = threadIdx.x;
    if (g >= 16) return;
    auto lower_bound = [&](int key) {
        int lo = 0, hi = N;
        while (lo < hi) { int mid = (lo + hi) >> 1; if (batch[mid] < key) lo = mid + 1; else hi = mid; }
        return lo;
    };
    cnt[g] = lower_bound(g + 1) - lower_bound(g);
}

__global__ void pool_kernel(const float* __restrict__ H, const int* __restrict__ batch,
                            float* __restrict__ sums, int N) {
    const int CHUNK = 256;
    int d = threadIdx.x;                  // 0..63
    int n0 = blockIdx.x * CHUNK;
    int n1 = min(n0 + CHUNK, N);
    int cur = batch[n0];
    float run = 0.f;
    for (int n = n0; n < n1; ++n) {
        int b = batch[n];                 // uniform
        float v = H[(size_t)n * 64 + d];
        if (b != cur) { atomicAdd(&sums[cur * 64 + d], run); run = 0.f; cur = b; }
        run += v;
    }
    atomicAdd(&sums[cur * 64 + d], run);
}

__global__ void finalize_kernel(const float* __restrict__ sums, const int* __restrict__ cnt,
                                float* __restrict__ out) {
    int i = blockIdx.x * blockDim.x + threadIdx.x;
    if (i < 1024) {
        float c = (float)max(cnt[i >> 6], 1);
        out[i] = sums[i] / c;
    }
}

// ---------------- launch ----------------

extern "C" void kernel_launch(void* const* d_in, const int* in_sizes, int n_in,
                              void* d_out, int out_size, void* d_ws, size_t ws_size,
                              hipStream_t stream) {
    const float* x   = (const float*)d_in[0];
    const int*   ei  = (const int*)d_in[1];
    const float* ea  = (const float*)d_in[2];
    const int*   bat = (const int*)d_in[3];
    const float* W1  = (const float*)d_in[4];
    const float* b1  = (const float*)d_in[5];
    const float* W2  = (const float*)d_in[6];
    const float* b2  = (const float*)d_in[7];
    const float* W3  = (const float*)d_in[8];
    const float* b3  = (const float*)d_in[9];

    const int N = in_sizes[0] / 128;
    const int E = in_sizes[2];
    const int* src = ei;
    const int* dst = ei + E;

    auto align = [](size_t v) { return (v + 255) & ~(size_t)255; };
    char* p = (char*)d_ws;
    float* H        = (float*)p; p += align((size_t)N * 128 * sizeof(float));
    float* O        = (float*)p; p += align((size_t)N * 128 * sizeof(float));
    int*   deg      = (int*)p;   p += align((size_t)N * sizeof(int));
    int*   row_off  = (int*)p;   p += align((size_t)(N + 1) * sizeof(int));
    int*   cursor   = (int*)p;   p += align((size_t)N * sizeof(int));
    int2*  csr      = (int2*)p;  p += align((size_t)E * sizeof(int2));
    int*   blk_sums = (int*)p;   p += align(128 * sizeof(int));
    float* sums     = (float*)p; p += align(1024 * sizeof(float));
    int*   cnt      = (int*)p;   p += align(16 * sizeof(int));

    hipMemsetAsync(deg, 0, (size_t)N * sizeof(int), stream);
    hipMemsetAsync(sums, 0, 1024 * sizeof(float), stream);

    int eb = (E + 255) / 256;
    int nb = (N + 1023) / 1024;
    hist_kernel<<<eb, 256, 0, stream>>>(dst, deg, E);
    scan1_kernel<<<nb, 1024, 0, stream>>>(deg, row_off, blk_sums, N);
    scan2_kernel<<<1, 128, 0, stream>>>(blk_sums, nb);
    scan3_kernel<<<nb, 1024, 0, stream>>>(row_off, blk_sums, cursor, N, E);
    build_csr_kernel<<<eb, 256, 0, stream>>>(src, dst, ea, cursor, csr, E);

    int gb = (N + 31) / 32;
    // layer 1
    gemm_bias_kernel<128><<<gb, 256, 0, stream>>>(x, W1, b1, H, N);
    aggregate_kernel<128><<<(N + 7) / 8, 256, 0, stream>>>(H, row_off, csr, O, N);
    // layer 2
    gemm_bias_kernel<128><<<gb, 256, 0, stream>>>(O, W2, b2, H, N);
    aggregate_kernel<128><<<(N + 7) / 8, 256, 0, stream>>>(H, row_off, csr, O, N);
    // layer 3 (DOUT = 64)
    gemm_bias_kernel<64><<<gb, 256, 0, stream>>>(O, W3, b3, H, N);
    aggregate_kernel<64><<<(N + 15) / 16, 256, 0, stream>>>(H, row_off, csr, O, N);

    // pool
    counts_kernel<<<1, 64, 0, stream>>>(bat, cnt, N);
    pool_kernel<<<(N + 255) / 256, 64, 0, stream>>>(O, bat, sums, N);
    finalize_kernel<<<4, 256, 0, stream>>>(sums, cnt, (float*)d_out);
}

// Round 5
// 463.723 us; speedup vs baseline: 2.9501x; 1.0842x over previous
//
#include <hip/hip_runtime.h>
#include <hip/hip_bf16.h>

// ---------------- CSR build ----------------

__global__ void hist_kernel(const int* __restrict__ dst, int* __restrict__ deg, int E) {
    int e = blockIdx.x * blockDim.x + threadIdx.x;
    if (e < E) atomicAdd(&deg[dst[e]], 1);
}

// two-pass scan: (1) per-block exclusive scan + block sums
__global__ __launch_bounds__(1024) void scan1_kernel(const int* __restrict__ deg,
                                                     int* __restrict__ row_off,
                                                     int* __restrict__ blk_sums, int N) {
    __shared__ int sd[1024];
    int tid = threadIdx.x;
    int i = blockIdx.x * 1024 + tid;
    int v = (i < N) ? deg[i] : 0;
    sd[tid] = v;
    __syncthreads();
    for (int off = 1; off < 1024; off <<= 1) {
        int t = (tid >= off) ? sd[tid - off] : 0;
        __syncthreads();
        sd[tid] += t;
        __syncthreads();
    }
    if (i < N) row_off[i] = sd[tid] - v;   // block-local exclusive
    if (tid == 1023) blk_sums[blockIdx.x] = sd[1023];
}

// (2) scan the block sums (nb <= 128)
__global__ void scan2_kernel(int* __restrict__ blk, int nb) {
    __shared__ int s[128];
    int t = threadIdx.x;
    int v = (t < nb) ? blk[t] : 0;
    s[t] = v;
    __syncthreads();
    for (int off = 1; off < 128; off <<= 1) {
        int u = (t >= off) ? s[t - off] : 0;
        __syncthreads();
        s[t] += u;
        __syncthreads();
    }
    if (t < nb) blk[t] = s[t] - v;         // exclusive block offsets
}

// (3) add block offsets, fill cursor, set row_off[N]=E
__global__ __launch_bounds__(1024) void scan3_kernel(int* __restrict__ row_off,
                                                     const int* __restrict__ blk_sums,
                                                     int* __restrict__ cursor, int N, int E) {
    int i = blockIdx.x * 1024 + threadIdx.x;
    if (i < N) {
        int r = row_off[i] + blk_sums[blockIdx.x];
        row_off[i] = r;
        cursor[i] = r;
    }
    if (i == 0) row_off[N] = E;
}

// csr[pos] = {src, w-as-int} interleaved -> one 8B uniform load per edge
__global__ void build_csr_kernel(const int* __restrict__ src, const int* __restrict__ dst,
                                 const float* __restrict__ ea, int* __restrict__ cursor,
                                 int2* __restrict__ csr, int E) {
    int e = blockIdx.x * blockDim.x + threadIdx.x;
    if (e < E) {
        int d = dst[e];
        int pos = atomicAdd(&cursor[d], 1);
        csr[pos] = make_int2(src[e], __float_as_int(ea[e]));
    }
}

// ---------------- GEMM: H = X @ W + b  (K = 128 fixed) ----------------

template <int DOUT>
__global__ __launch_bounds__(256) void gemm_bias_kernel(
    const float* __restrict__ X, const float* __restrict__ W,
    const float* __restrict__ b, float* __restrict__ H, int N) {
    constexpr int ROWS = 32;
    constexpr int RPT = ROWS * DOUT / 256;   // rows per thread
    __shared__ float xs[ROWS][128];
    int tid = threadIdx.x;
    int row0 = blockIdx.x * ROWS;

    const float4* Xv = reinterpret_cast<const float4*>(X);
#pragma unroll
    for (int j = 0; j < 4; j++) {
        int idx = tid + j * 256;
        int r = idx >> 5;
        int c4 = idx & 31;
        float4 v = make_float4(0.f, 0.f, 0.f, 0.f);
        int row = row0 + r;
        if (row < N) v = Xv[(size_t)row * 32 + c4];
        *reinterpret_cast<float4*>(&xs[r][c4 * 4]) = v;
    }
    __syncthreads();

    int c = tid % DOUT;
    int rg = tid / DOUT;
    float acc[RPT];
#pragma unroll
    for (int i = 0; i < RPT; i++) acc[i] = 0.f;

    // k in chunks of 4: ds_read_b128 on the x-tile, 4 coalesced W loads
#pragma unroll 4
    for (int k4 = 0; k4 < 32; k4++) {
        float w0 = W[(4 * k4 + 0) * DOUT + c];
        float w1 = W[(4 * k4 + 1) * DOUT + c];
        float w2 = W[(4 * k4 + 2) * DOUT + c];
        float w3 = W[(4 * k4 + 3) * DOUT + c];
#pragma unroll
        for (int i = 0; i < RPT; i++) {
            float4 xv = *reinterpret_cast<const float4*>(&xs[rg * RPT + i][k4 * 4]);
            acc[i] += xv.x * w0 + xv.y * w1 + xv.z * w2 + xv.w * w3;
        }
    }
    float bb = b[c];
#pragma unroll
    for (int i = 0; i < RPT; i++) {
        int row = row0 + rg * RPT + i;
        if (row < N) H[(size_t)row * DOUT + c] = acc[i] + bb;
    }
}

// ---------------- Aggregate: OUT[n] = H[n] + sum_{e: dst=n} H[src_e] * w_e ----------------
// float4 per lane (TPN = D/4 threads per node), 4-way edge unroll for MLP.

template <int D>
__global__ __launch_bounds__(256) void aggregate_kernel(
    const float* __restrict__ H, const int* __restrict__ row_off,
    const int2* __restrict__ csr, float* __restrict__ OUT, int N) {
    constexpr int TPN = D / 4;              // threads per node
    constexpr int NPB = 256 / TPN;          // nodes per block
    int n = blockIdx.x * NPB + threadIdx.x / TPN;
    int d4 = threadIdx.x % TPN;
    if (n >= N) return;
    const float4* Hv = reinterpret_cast<const float4*>(H);
    float4 acc = Hv[(size_t)n * TPN + d4];
    int e = row_off[n];
    int e1 = row_off[n + 1];
    for (; e + 4 <= e1; e += 4) {
        int2 c0 = csr[e], c1 = csr[e + 1], c2 = csr[e + 2], c3 = csr[e + 3];
        float4 v0 = Hv[(size_t)c0.x * TPN + d4];
        float4 v1 = Hv[(size_t)c1.x * TPN + d4];
        float4 v2 = Hv[(size_t)c2.x * TPN + d4];
        float4 v3 = Hv[(size_t)c3.x * TPN + d4];
        float w0 = __int_as_float(c0.y), w1 = __int_as_float(c1.y);
        float w2 = __int_as_float(c2.y), w3 = __int_as_float(c3.y);
        acc.x += v0.x * w0 + v1.x * w1 + v2.x * w2 + v3.x * w3;
        acc.y += v0.y * w0 + v1.y * w1 + v2.y * w2 + v3.y * w3;
        acc.z += v0.z * w0 + v1.z * w1 + v2.z * w2 + v3.z * w3;
        acc.w += v0.w * w0 + v1.w * w1 + v2.w * w2 + v3.w * w3;
    }
    for (; e < e1; ++e) {
        int2 c = csr[e];
        float4 v = Hv[(size_t)c.x * TPN + d4];
        float w = __int_as_float(c.y);
        acc.x += v.x * w; acc.y += v.y * w; acc.z += v.z * w; acc.w += v.w * w;
    }
    reinterpret_cast<float4*>(OUT)[(size_t)n * TPN + d4] = acc;
}

// ---------------- Pool ----------------

// batch is sorted: counts = boundary differences via binary search (no atomics)
__global__ void counts_kernel(const int* __restrict__ batch, int* __restrict__ cnt, int N) {
    int g = threadIdx.x;
    if (g >= 16) return;
    auto lower_bound = [&](int key) {
        int lo = 0, hi = N;
        while (lo < hi) { int mid = (lo + hi) >> 1; if (batch[mid] < key) lo = mid + 1; else hi = mid; }
        return lo;
    };
    cnt[g] = lower_bound(g + 1) - lower_bound(g);
}

// 256 threads = 16 row-lanes x 16 float4-lanes; register run + LDS bins + one
// global atomic pass per block.
__global__ __launch_bounds__(256) void pool_kernel(const float* __restrict__ H,
                                                   const int* __restrict__ batch,
                                                   float* __restrict__ sums, int N,
                                                   int rows_per_blk) {
    __shared__ float bins[16 * 64];
    int tid = threadIdx.x;
    for (int i = tid; i < 1024; i += 256) bins[i] = 0.f;
    __syncthreads();
    int d4 = tid & 15;
    int rl = tid >> 4;
    int n0 = blockIdx.x * rows_per_blk;
    int n1 = min(n0 + rows_per_blk, N);
    const float4* Hv = reinterpret_cast<const float4*>(H);
    float4 run = make_float4(0.f, 0.f, 0.f, 0.f);
    int cur = -1;
    for (int n = n0 + rl; n < n1; n += 16) {
        int b = batch[n];
        if (b != cur) {
            if (cur >= 0) {
                atomicAdd(&bins[cur * 64 + d4 * 4 + 0], run.x);
                atomicAdd(&bins[cur * 64 + d4 * 4 + 1], run.y);
                atomicAdd(&bins[cur * 64 + d4 * 4 + 2], run.z);
                atomicAdd(&bins[cur * 64 + d4 * 4 + 3], run.w);
            }
            cur = b;
            run = make_float4(0.f, 0.f, 0.f, 0.f);
        }
        float4 v = Hv[(size_t)n * 16 + d4];
        run.x += v.x; run.y += v.y; run.z += v.z; run.w += v.w;
    }
    if (cur >= 0) {
        atomicAdd(&bins[cur * 64 + d4 * 4 + 0], run.x);
        atomicAdd(&bins[cur * 64 + d4 * 4 + 1], run.y);
        atomicAdd(&bins[cur * 64 + d4 * 4 + 2], run.z);
        atomicAdd(&bins[cur * 64 + d4 * 4 + 3], run.w);
    }
    __syncthreads();
    for (int i = tid; i < 1024; i += 256) {
        float v = bins[i];
        if (v != 0.f) atomicAdd(&sums[i], v);
    }
}

__global__ void finalize_kernel(const float* __restrict__ sums, const int* __restrict__ cnt,
                                float* __restrict__ out) {
    int i = blockIdx.x * blockDim.x + threadIdx.x;
    if (i < 1024) {
        float c = (float)max(cnt[i >> 6], 1);
        out[i] = sums[i] / c;
    }
}

// ---------------- launch ----------------

extern "C" void kernel_launch(void* const* d_in, const int* in_sizes, int n_in,
                              void* d_out, int out_size, void* d_ws, size_t ws_size,
                              hipStream_t stream) {
    const float* x   = (const float*)d_in[0];
    const int*   ei  = (const int*)d_in[1];
    const float* ea  = (const float*)d_in[2];
    const int*   bat = (const int*)d_in[3];
    const float* W1  = (const float*)d_in[4];
    const float* b1  = (const float*)d_in[5];
    const float* W2  = (const float*)d_in[6];
    const float* b2  = (const float*)d_in[7];
    const float* W3  = (const float*)d_in[8];
    const float* b3  = (const float*)d_in[9];

    const int N = in_sizes[0] / 128;
    const int E = in_sizes[2];
    const int* src = ei;
    const int* dst = ei + E;

    auto align = [](size_t v) { return (v + 255) & ~(size_t)255; };
    char* p = (char*)d_ws;
    float* H        = (float*)p; p += align((size_t)N * 128 * sizeof(float));
    float* O        = (float*)p; p += align((size_t)N * 128 * sizeof(float));
    int*   deg      = (int*)p;   p += align((size_t)N * sizeof(int));
    int*   row_off  = (int*)p;   p += align((size_t)(N + 1) * sizeof(int));
    int*   cursor   = (int*)p;   p += align((size_t)N * sizeof(int));
    int2*  csr      = (int2*)p;  p += align((size_t)E * sizeof(int2));
    int*   blk_sums = (int*)p;   p += align(128 * sizeof(int));
    float* sums     = (float*)p; p += align(1024 * sizeof(float));
    int*   cnt      = (int*)p;   p += align(16 * sizeof(int));

    hipMemsetAsync(deg, 0, (size_t)N * sizeof(int), stream);
    hipMemsetAsync(sums, 0, 1024 * sizeof(float), stream);

    int eb = (E + 255) / 256;
    int nb = (N + 1023) / 1024;
    hist_kernel<<<eb, 256, 0, stream>>>(dst, deg, E);
    scan1_kernel<<<nb, 1024, 0, stream>>>(deg, row_off, blk_sums, N);
    scan2_kernel<<<1, 128, 0, stream>>>(blk_sums, nb);
    scan3_kernel<<<nb, 1024, 0, stream>>>(row_off, blk_sums, cursor, N, E);
    build_csr_kernel<<<eb, 256, 0, stream>>>(src, dst, ea, cursor, csr, E);

    int gb = (N + 31) / 32;
    // layer 1
    gemm_bias_kernel<128><<<gb, 256, 0, stream>>>(x, W1, b1, H, N);
    aggregate_kernel<128><<<(N + 7) / 8, 256, 0, stream>>>(H, row_off, csr, O, N);
    // layer 2
    gemm_bias_kernel<128><<<gb, 256, 0, stream>>>(O, W2, b2, H, N);
    aggregate_kernel<128><<<(N + 7) / 8, 256, 0, stream>>>(H, row_off, csr, O, N);
    // layer 3 (DOUT = 64)
    gemm_bias_kernel<64><<<gb, 256, 0, stream>>>(O, W3, b3, H, N);
    aggregate_kernel<64><<<(N + 15) / 16, 256, 0, stream>>>(H, row_off, csr, O, N);

    // pool
    counts_kernel<<<1, 64, 0, stream>>>(bat, cnt, N);
    int pool_blocks = 512;
    int rows_per_blk = (N + pool_blocks - 1) / pool_blocks;
    pool_kernel<<<pool_blocks, 256, 0, stream>>>(O, bat, sums, N, rows_per_blk);
    finalize_kernel<<<4, 256, 0, stream>>>(sums, cnt, (float*)d_out);
}

// Round 9
// 322.969 us; speedup vs baseline: 4.2359x; 1.4358x over previous
//
#include <hip/hip_runtime.h>
#include <hip/hip_bf16.h>

typedef __bf16 bf16x8 __attribute__((ext_vector_type(8)));
typedef float f32x4 __attribute__((ext_vector_type(4)));

__device__ __forceinline__ unsigned short f2bf(float f) {
    unsigned int u = __float_as_uint(f);
    unsigned int r = (u + 0x7FFFu + ((u >> 16) & 1u)) >> 16;   // RNE
    return (unsigned short)r;
}
__device__ __forceinline__ float bflo(unsigned int u) { return __uint_as_float(u << 16); }
__device__ __forceinline__ float bfhi(unsigned int u) { return __uint_as_float(u & 0xffff0000u); }

// ---------------- CSR build ----------------

__global__ void hist_kernel(const int* __restrict__ dst, int* __restrict__ deg, int E) {
    int e = blockIdx.x * blockDim.x + threadIdx.x;
    if (e < E) atomicAdd(&deg[dst[e]], 1);
}

__global__ __launch_bounds__(1024) void scan1_kernel(const int* __restrict__ deg,
                                                     int* __restrict__ row_off,
                                                     int* __restrict__ blk_sums, int N) {
    __shared__ int sd[1024];
    int tid = threadIdx.x;
    int i = blockIdx.x * 1024 + tid;
    int v = (i < N) ? deg[i] : 0;
    sd[tid] = v;
    __syncthreads();
    for (int off = 1; off < 1024; off <<= 1) {
        int t = (tid >= off) ? sd[tid - off] : 0;
        __syncthreads();
        sd[tid] += t;
        __syncthreads();
    }
    if (i < N) row_off[i] = sd[tid] - v;
    if (tid == 1023) blk_sums[blockIdx.x] = sd[1023];
}

__global__ void scan2_kernel(int* __restrict__ blk, int nb) {
    __shared__ int s[128];
    int t = threadIdx.x;
    int v = (t < nb) ? blk[t] : 0;
    s[t] = v;
    __syncthreads();
    for (int off = 1; off < 128; off <<= 1) {
        int u = (t >= off) ? s[t - off] : 0;
        __syncthreads();
        s[t] += u;
        __syncthreads();
    }
    if (t < nb) blk[t] = s[t] - v;
}

__global__ __launch_bounds__(1024) void scan3_kernel(int* __restrict__ row_off,
                                                     const int* __restrict__ blk_sums,
                                                     int* __restrict__ cursor, int N, int E) {
    int i = blockIdx.x * 1024 + threadIdx.x;
    if (i < N) {
        int r = row_off[i] + blk_sums[blockIdx.x];
        row_off[i] = r;
        cursor[i] = r;
    }
    if (i == 0) row_off[N] = E;
}

__global__ void build_csr_kernel(const int* __restrict__ src, const int* __restrict__ dst,
                                 const float* __restrict__ ea, int* __restrict__ cursor,
                                 int2* __restrict__ csr, int E) {
    int e = blockIdx.x * blockDim.x + threadIdx.x;
    if (e < E) {
        int d = dst[e];
        int pos = atomicAdd(&cursor[d], 1);
        csr[pos] = make_int2(src[e], __float_as_int(ea[e]));
    }
}

// ---------------- dtype prep ----------------

// x f32 -> bf16 (n divisible by 4)
__global__ void f32_to_bf16_kernel(const float* __restrict__ in, unsigned short* __restrict__ out,
                                   int n4) {
    int i = blockIdx.x * blockDim.x + threadIdx.x;
    if (i >= n4) return;
    float4 v = reinterpret_cast<const float4*>(in)[i];
    ushort4 o;
    o.x = f2bf(v.x); o.y = f2bf(v.y); o.z = f2bf(v.z); o.w = f2bf(v.w);
    reinterpret_cast<ushort4*>(out)[i] = o;
}

// W [128][DOUT] f32 -> Wt bf16, transposed+swizzled:
// element offset = col*128 + ((kblk ^ (col&7))*8) + j, holding W[kblk*8+j][col]
template <int DOUT>
__global__ void prep_w_kernel(const float* __restrict__ W, unsigned short* __restrict__ Wt) {
    int i = blockIdx.x * blockDim.x + threadIdx.x;   // (col, kblk)
    if (i >= DOUT * 16) return;
    int col = i >> 4;
    int kblk = i & 15;
    size_t off = (size_t)col * 128 + (size_t)((kblk ^ (col & 7)) << 3);
#pragma unroll
    for (int j = 0; j < 8; j++)
        Wt[off + j] = f2bf(W[(kblk * 8 + j) * DOUT + col]);
}

// ---------------- GEMM (MFMA bf16): Hb = bf16(Xb @ W + b) ----------------
// block = 256 thr = 4 waves, 64 rows/block (16/wave), all DOUT cols per wave.

template <int DOUT>
__global__ __launch_bounds__(256) void gemm_mfma_kernel(
    const unsigned short* __restrict__ Xb,   // [N][128] bf16
    const unsigned short* __restrict__ Wt,   // swizzled [DOUT][128] bf16
    const float* __restrict__ bias,
    unsigned short* __restrict__ Hb,         // [N][DOUT] bf16
    int N) {
    constexpr int CB = DOUT / 16;
    __shared__ unsigned short wlds[DOUT * 128];
    int tid = threadIdx.x;

    constexpr int TOT16 = DOUT * 128 / 8;    // 16B units
    const uint4* Wv = reinterpret_cast<const uint4*>(Wt);
    uint4* Lv = reinterpret_cast<uint4*>(wlds);
#pragma unroll
    for (int i = 0; i < TOT16 / 256; i++) Lv[tid + i * 256] = Wv[tid + i * 256];
    __syncthreads();

    int wave = tid >> 6;
    int lane = tid & 63;
    int r0 = blockIdx.x * 64 + wave * 16;
    int arow = r0 + (lane & 15);
    int arow_c = (arow < N) ? arow : (N - 1);   // clamped loads; stores guarded

    f32x4 acc[CB];
#pragma unroll
    for (int cb = 0; cb < CB; cb++) acc[cb] = (f32x4){0.f, 0.f, 0.f, 0.f};

    const bf16x8* Xrow = reinterpret_cast<const bf16x8*>(Xb + (size_t)arow_c * 128);
    int lhi = lane >> 4;                      // k-group 0..3
#pragma unroll
    for (int kk = 0; kk < 4; kk++) {
        bf16x8 a = Xrow[kk * 4 + lhi];        // k = kk*32 + lhi*8 .. +8
#pragma unroll
        for (int cb = 0; cb < CB; cb++) {
            int colg = cb * 16 + (lane & 15);
            int kblk = kk * 4 + lhi;
            const bf16x8* bp = reinterpret_cast<const bf16x8*>(
                &wlds[colg * 128 + ((kblk ^ (colg & 7)) << 3)]);
            acc[cb] = __builtin_amdgcn_mfma_f32_16x16x32_bf16(a, *bp, acc[cb], 0, 0, 0);
        }
    }

    // C/D: col = lane&15, row = (lane>>4)*4 + r   [m89 verified]
    int cl = lane & 15;
    int rbase = r0 + lhi * 4;
#pragma unroll
    for (int cb = 0; cb < CB; cb++) {
        int colg = cb * 16 + cl;
        float bb = bias[colg];
#pragma unroll
        for (int r = 0; r < 4; r++) {
            int rowg = rbase + r;
            if (rowg < N) Hb[(size_t)rowg * DOUT + colg] = f2bf(acc[cb][r] + bb);
        }
    }
}

// ---------------- Aggregate (bf16 table): Ob = bf16(Hb[n] + sum w*Hb[src]) ----------------
// TPN = D/8 lanes per node, each lane owns 8 bf16 (one uint4 / 16 B).

template <int D>
__global__ __launch_bounds__(256) void aggregate_bf16_kernel(
    const unsigned short* __restrict__ Hb, const int* __restrict__ row_off,
    const int2* __restrict__ csr, unsigned short* __restrict__ Ob, int N) {
    constexpr int TPN = D / 8;
    constexpr int NPB = 256 / TPN;
    int n = blockIdx.x * NPB + threadIdx.x / TPN;
    int d8 = threadIdx.x % TPN;
    if (n >= N) return;
    const uint4* Hv = reinterpret_cast<const uint4*>(Hb);

    float acc[8];
    {
        uint4 s = Hv[(size_t)n * TPN + d8];
        acc[0] = bflo(s.x); acc[1] = bfhi(s.x);
        acc[2] = bflo(s.y); acc[3] = bfhi(s.y);
        acc[4] = bflo(s.z); acc[5] = bfhi(s.z);
        acc[6] = bflo(s.w); acc[7] = bfhi(s.w);
    }
    auto madd = [&](uint4 v, float w) {
        acc[0] += bflo(v.x) * w; acc[1] += bfhi(v.x) * w;
        acc[2] += bflo(v.y) * w; acc[3] += bfhi(v.y) * w;
        acc[4] += bflo(v.z) * w; acc[5] += bfhi(v.z) * w;
        acc[6] += bflo(v.w) * w; acc[7] += bfhi(v.w) * w;
    };
    int e = row_off[n];
    int e1 = row_off[n + 1];
    for (; e + 4 <= e1; e += 4) {
        int2 c0 = csr[e], c1 = csr[e + 1], c2 = csr[e + 2], c3 = csr[e + 3];
        uint4 v0 = Hv[(size_t)c0.x * TPN + d8];
        uint4 v1 = Hv[(size_t)c1.x * TPN + d8];
        uint4 v2 = Hv[(size_t)c2.x * TPN + d8];
        uint4 v3 = Hv[(size_t)c3.x * TPN + d8];
        madd(v0, __int_as_float(c0.y));
        madd(v1, __int_as_float(c1.y));
        madd(v2, __int_as_float(c2.y));
        madd(v3, __int_as_float(c3.y));
    }
    for (; e < e1; ++e) {
        int2 c = csr[e];
        madd(Hv[(size_t)c.x * TPN + d8], __int_as_float(c.y));
    }
    uint4 o;
    o.x = (unsigned int)f2bf(acc[0]) | ((unsigned int)f2bf(acc[1]) << 16);
    o.y = (unsigned int)f2bf(acc[2]) | ((unsigned int)f2bf(acc[3]) << 16);
    o.z = (unsigned int)f2bf(acc[4]) | ((unsigned int)f2bf(acc[5]) << 16);
    o.w = (unsigned int)f2bf(acc[6]) | ((unsigned int)f2bf(acc[7]) << 16);
    reinterpret_cast<uint4*>(Ob)[(size_t)n * TPN + d8] = o;
}

// ---------------- Pool ----------------

__global__ void counts_kernel(const int* __restrict__ batch, int* __restrict__ cnt, int N) {
    int g = threadIdx.x;
    if (g >= 16) return;
    auto lower_bound = [&](int key) {
        int lo = 0, hi = N;
        while (lo < hi) { int mid = (lo + hi) >> 1; if (batch[mid] < key) lo = mid + 1; else hi = mid; }
        return lo;
    };
    cnt[g] = lower_bound(g + 1) - lower_bound(g);
}

// input: bf16 [N][64]. 16 row-lanes x 16 col-lanes (4 bf16 each).
__global__ __launch_bounds__(256) void pool_kernel(const unsigned short* __restrict__ Hb,
                                                   const int* __restrict__ batch,
                                                   float* __restrict__ sums, int N,
                                                   int rows_per_blk) {
    __shared__ float bins[16 * 64];
    int tid = threadIdx.x;
    for (int i = tid; i < 1024; i += 256) bins[i] = 0.f;
    __syncthreads();
    int d4 = tid & 15;
    int rl = tid >> 4;
    int n0 = blockIdx.x * rows_per_blk;
    int n1 = min(n0 + rows_per_blk, N);
    const uint2* Hv = reinterpret_cast<const uint2*>(Hb);   // 4 bf16 per uint2
    float r0 = 0.f, r1 = 0.f, r2 = 0.f, r3 = 0.f;
    int cur = -1;
    for (int n = n0 + rl; n < n1; n += 16) {
        int b = batch[n];
        if (b != cur) {
            if (cur >= 0) {
                atomicAdd(&bins[cur * 64 + d4 * 4 + 0], r0);
                atomicAdd(&bins[cur * 64 + d4 * 4 + 1], r1);
                atomicAdd(&bins[cur * 64 + d4 * 4 + 2], r2);
                atomicAdd(&bins[cur * 64 + d4 * 4 + 3], r3);
            }
            cur = b;
            r0 = r1 = r2 = r3 = 0.f;
        }
        uint2 v = Hv[(size_t)n * 16 + d4];
        r0 += bflo(v.x); r1 += bfhi(v.x); r2 += bflo(v.y); r3 += bfhi(v.y);
    }
    if (cur >= 0) {
        atomicAdd(&bins[cur * 64 + d4 * 4 + 0], r0);
        atomicAdd(&bins[cur * 64 + d4 * 4 + 1], r1);
        atomicAdd(&bins[cur * 64 + d4 * 4 + 2], r2);
        atomicAdd(&bins[cur * 64 + d4 * 4 + 3], r3);
    }
    __syncthreads();
    for (int i = tid; i < 1024; i += 256) {
        float v = bins[i];
        if (v != 0.f) atomicAdd(&sums[i], v);
    }
}

__global__ void finalize_kernel(const float* __restrict__ sums, const int* __restrict__ cnt,
                                float* __restrict__ out) {
    int i = blockIdx.x * blockDim.x + threadIdx.x;
    if (i < 1024) {
        float c = (float)max(cnt[i >> 6], 1);
        out[i] = sums[i] / c;
    }
}

// ---------------- launch ----------------

extern "C" void kernel_launch(void* const* d_in, const int* in_sizes, int n_in,
                              void* d_out, int out_size, void* d_ws, size_t ws_size,
                              hipStream_t stream) {
    const float* x   = (const float*)d_in[0];
    const int*   ei  = (const int*)d_in[1];
    const float* ea  = (const float*)d_in[2];
    const int*   bat = (const int*)d_in[3];
    const float* W1  = (const float*)d_in[4];
    const float* b1  = (const float*)d_in[5];
    const float* W2  = (const float*)d_in[6];
    const float* b2  = (const float*)d_in[7];
    const float* W3  = (const float*)d_in[8];
    const float* b3  = (const float*)d_in[9];

    const int N = in_sizes[0] / 128;
    const int E = in_sizes[2];
    const int* src = ei;
    const int* dst = ei + E;

    auto align = [](size_t v) { return (v + 255) & ~(size_t)255; };
    char* p = (char*)d_ws;
    unsigned short* Xb   = (unsigned short*)p; p += align((size_t)N * 128 * 2);
    unsigned short* Hb   = (unsigned short*)p; p += align((size_t)N * 128 * 2);  // also holds [N][64] for layer 3
    unsigned short* Ab   = (unsigned short*)p; p += align((size_t)N * 128 * 2);
    unsigned short* Ab3  = (unsigned short*)p; p += align((size_t)N * 64 * 2);
    unsigned short* Wt1  = (unsigned short*)p; p += align(128 * 128 * 2);
    unsigned short* Wt2  = (unsigned short*)p; p += align(128 * 128 * 2);
    unsigned short* Wt3  = (unsigned short*)p; p += align(64 * 128 * 2);
    int*   deg      = (int*)p;   p += align((size_t)N * sizeof(int));
    int*   row_off  = (int*)p;   p += align((size_t)(N + 1) * sizeof(int));
    int*   cursor   = (int*)p;   p += align((size_t)N * sizeof(int));
    int2*  csr      = (int2*)p;  p += align((size_t)E * sizeof(int2));
    int*   blk_sums = (int*)p;   p += align(128 * sizeof(int));
    float* sums     = (float*)p; p += align(1024 * sizeof(float));
    int*   cnt      = (int*)p;   p += align(16 * sizeof(int));

    hipMemsetAsync(deg, 0, (size_t)N * sizeof(int), stream);
    hipMemsetAsync(sums, 0, 1024 * sizeof(float), stream);

    int eb = (E + 255) / 256;
    int nb = (N + 1023) / 1024;
    hist_kernel<<<eb, 256, 0, stream>>>(dst, deg, E);
    scan1_kernel<<<nb, 1024, 0, stream>>>(deg, row_off, blk_sums, N);
    scan2_kernel<<<1, 128, 0, stream>>>(blk_sums, nb);
    scan3_kernel<<<nb, 1024, 0, stream>>>(row_off, blk_sums, cursor, N, E);
    build_csr_kernel<<<eb, 256, 0, stream>>>(src, dst, ea, cursor, csr, E);

    // dtype prep
    int n4 = N * 128 / 4;
    f32_to_bf16_kernel<<<(n4 + 255) / 256, 256, 0, stream>>>(x, Xb, n4);
    prep_w_kernel<128><<<(128 * 16 + 255) / 256, 256, 0, stream>>>(W1, Wt1);
    prep_w_kernel<128><<<(128 * 16 + 255) / 256, 256, 0, stream>>>(W2, Wt2);
    prep_w_kernel<64><<<(64 * 16 + 255) / 256, 256, 0, stream>>>(W3, Wt3);

    int gb = (N + 63) / 64;
    // layer 1
    gemm_mfma_kernel<128><<<gb, 256, 0, stream>>>(Xb, Wt1, b1, Hb, N);
    aggregate_bf16_kernel<128><<<(N + 15) / 16, 256, 0, stream>>>(Hb, row_off, csr, Ab, N);
    // layer 2
    gemm_mfma_kernel<128><<<gb, 256, 0, stream>>>(Ab, Wt2, b2, Hb, N);
    aggregate_bf16_kernel<128><<<(N + 15) / 16, 256, 0, stream>>>(Hb, row_off, csr, Ab, N);
    // layer 3 (DOUT = 64)
    gemm_mfma_kernel<64><<<gb, 256, 0, stream>>>(Ab, Wt3, b3, Hb, N);
    aggregate_bf16_kernel<64><<<(N + 31) / 32, 256, 0, stream>>>(Hb, row_off, csr, Ab3, N);

    // pool
    counts_kernel<<<1, 64, 0, stream>>>(bat, cnt, N);
    int pool_blocks = 512;
    int rows_per_blk = (N + pool_blocks - 1) / pool_blocks;
    pool_kernel<<<pool_blocks, 256, 0, stream>>>(Ab3, bat, sums, N, rows_per_blk);
    finalize_kernel<<<4, 256, 0, stream>>>(sums, cnt, (float*)d_out);
}

// Round 10
// 301.519 us; speedup vs baseline: 4.5372x; 1.0711x over previous
//
#include <hip/hip_runtime.h>
#include <hip/hip_bf16.h>

typedef __bf16 bf16x8 __attribute__((ext_vector_type(8)));
typedef float f32x4 __attribute__((ext_vector_type(4)));

__device__ __forceinline__ unsigned short f2bf(float f) {
    unsigned int u = __float_as_uint(f);
    unsigned int r = (u + 0x7FFFu + ((u >> 16) & 1u)) >> 16;   // RNE
    return (unsigned short)r;
}
__device__ __forceinline__ float bflo(unsigned int u) { return __uint_as_float(u << 16); }
__device__ __forceinline__ float bfhi(unsigned int u) { return __uint_as_float(u & 0xffff0000u); }

// ---------------- fused prep: x->bf16 | hist | W1/W2/W3 transpose+swizzle ----------------

__device__ __forceinline__ void prep_w_dev(const float* __restrict__ W,
                                           unsigned short* __restrict__ Wt,
                                           int DOUT, int i) {
    // i in [0, DOUT*16): (col, kblk)
    int col = i >> 4;
    int kblk = i & 15;
    size_t off = (size_t)col * 128 + (size_t)((kblk ^ (col & 7)) << 3);
#pragma unroll
    for (int j = 0; j < 8; j++)
        Wt[off + j] = f2bf(W[(kblk * 8 + j) * DOUT + col]);
}

__global__ __launch_bounds__(256) void prep_kernel(
    const float* __restrict__ x, unsigned short* __restrict__ Xb, int n4, int xblocks,
    const int* __restrict__ dst, int* __restrict__ deg, int E, int eblocks,
    const float* __restrict__ W1, unsigned short* __restrict__ Wt1,
    const float* __restrict__ W2, unsigned short* __restrict__ Wt2,
    const float* __restrict__ W3, unsigned short* __restrict__ Wt3) {
    int b = blockIdx.x;
    int tid = threadIdx.x;
    if (b < xblocks) {
        int i = b * 256 + tid;
        if (i < n4) {
            float4 v = reinterpret_cast<const float4*>(x)[i];
            ushort4 o;
            o.x = f2bf(v.x); o.y = f2bf(v.y); o.z = f2bf(v.z); o.w = f2bf(v.w);
            reinterpret_cast<ushort4*>(Xb)[i] = o;
        }
        return;
    }
    b -= xblocks;
    if (b < eblocks) {
        int e = b * 256 + tid;
        if (e < E) atomicAdd(&deg[dst[e]], 1);
        return;
    }
    b -= eblocks;
    // W1: blocks 0..7, W2: 8..15, W3: 16..19
    if (b < 8) {
        prep_w_dev(W1, Wt1, 128, b * 256 + tid);
    } else if (b < 16) {
        prep_w_dev(W2, Wt2, 128, (b - 8) * 256 + tid);
    } else {
        int i = (b - 16) * 256 + tid;
        if (i < 64 * 16) prep_w_dev(W3, Wt3, 64, i);
    }
}

// ---------------- CSR build ----------------

__global__ __launch_bounds__(1024) void scan1_kernel(const int* __restrict__ deg,
                                                     int* __restrict__ row_off,
                                                     int* __restrict__ blk_sums, int N) {
    __shared__ int sd[1024];
    int tid = threadIdx.x;
    int i = blockIdx.x * 1024 + tid;
    int v = (i < N) ? deg[i] : 0;
    sd[tid] = v;
    __syncthreads();
    for (int off = 1; off < 1024; off <<= 1) {
        int t = (tid >= off) ? sd[tid - off] : 0;
        __syncthreads();
        sd[tid] += t;
        __syncthreads();
    }
    if (i < N) row_off[i] = sd[tid] - v;
    if (tid == 1023) blk_sums[blockIdx.x] = sd[1023];
}

__global__ void scan2_kernel(int* __restrict__ blk, int nb) {
    __shared__ int s[128];
    int t = threadIdx.x;
    int v = (t < nb) ? blk[t] : 0;
    s[t] = v;
    __syncthreads();
    for (int off = 1; off < 128; off <<= 1) {
        int u = (t >= off) ? s[t - off] : 0;
        __syncthreads();
        s[t] += u;
        __syncthreads();
    }
    if (t < nb) blk[t] = s[t] - v;
}

__global__ __launch_bounds__(1024) void scan3_kernel(int* __restrict__ row_off,
                                                     const int* __restrict__ blk_sums,
                                                     int* __restrict__ cursor, int N, int E) {
    int i = blockIdx.x * 1024 + threadIdx.x;
    if (i < N) {
        int r = row_off[i] + blk_sums[blockIdx.x];
        row_off[i] = r;
        cursor[i] = r;
    }
    if (i == 0) row_off[N] = E;
}

// packed entry: low16 = src (N < 65536), high16 = bf16 weight
__global__ void build_csr_kernel(const int* __restrict__ src, const int* __restrict__ dst,
                                 const float* __restrict__ ea, int* __restrict__ cursor,
                                 unsigned int* __restrict__ csr, int E) {
    int e = blockIdx.x * blockDim.x + threadIdx.x;
    if (e < E) {
        int d = dst[e];
        int pos = atomicAdd(&cursor[d], 1);
        csr[pos] = (unsigned int)src[e] | ((unsigned int)f2bf(ea[e]) << 16);
    }
}

// ---------------- GEMM (MFMA bf16): Hb = bf16(Xb @ W + b) ----------------

template <int DOUT>
__global__ __launch_bounds__(256) void gemm_mfma_kernel(
    const unsigned short* __restrict__ Xb,   // [N][128] bf16
    const unsigned short* __restrict__ Wt,   // swizzled [DOUT][128] bf16
    const float* __restrict__ bias,
    unsigned short* __restrict__ Hb,         // [N][DOUT] bf16
    int N) {
    constexpr int CB = DOUT / 16;
    __shared__ unsigned short wlds[DOUT * 128];
    int tid = threadIdx.x;

    constexpr int TOT16 = DOUT * 128 / 8;    // 16B units
    const uint4* Wv = reinterpret_cast<const uint4*>(Wt);
    uint4* Lv = reinterpret_cast<uint4*>(wlds);
#pragma unroll
    for (int i = 0; i < TOT16 / 256; i++) Lv[tid + i * 256] = Wv[tid + i * 256];
    __syncthreads();

    int wave = tid >> 6;
    int lane = tid & 63;
    int r0 = blockIdx.x * 64 + wave * 16;
    int arow = r0 + (lane & 15);
    int arow_c = (arow < N) ? arow : (N - 1);   // clamped loads; stores guarded

    f32x4 acc[CB];
#pragma unroll
    for (int cb = 0; cb < CB; cb++) acc[cb] = (f32x4){0.f, 0.f, 0.f, 0.f};

    const bf16x8* Xrow = reinterpret_cast<const bf16x8*>(Xb + (size_t)arow_c * 128);
    int lhi = lane >> 4;                      // k-group 0..3
#pragma unroll
    for (int kk = 0; kk < 4; kk++) {
        bf16x8 a = Xrow[kk * 4 + lhi];        // k = kk*32 + lhi*8 .. +8
#pragma unroll
        for (int cb = 0; cb < CB; cb++) {
            int colg = cb * 16 + (lane & 15);
            int kblk = kk * 4 + lhi;
            const bf16x8* bp = reinterpret_cast<const bf16x8*>(
                &wlds[colg * 128 + ((kblk ^ (colg & 7)) << 3)]);
            acc[cb] = __builtin_amdgcn_mfma_f32_16x16x32_bf16(a, *bp, acc[cb], 0, 0, 0);
        }
    }

    // C/D: col = lane&15, row = (lane>>4)*4 + r   [m89 verified]
    int cl = lane & 15;
    int rbase = r0 + lhi * 4;
#pragma unroll
    for (int cb = 0; cb < CB; cb++) {
        int colg = cb * 16 + cl;
        float bb = bias[colg];
#pragma unroll
        for (int r = 0; r < 4; r++) {
            int rowg = rbase + r;
            if (rowg < N) Hb[(size_t)rowg * DOUT + colg] = f2bf(acc[cb][r] + bb);
        }
    }
}

// ---------------- Aggregate (bf16 table): Ob = bf16(Hb[n] + sum w*Hb[src]) ----------------

template <int D>
__global__ __launch_bounds__(256) void aggregate_bf16_kernel(
    const unsigned short* __restrict__ Hb, const int* __restrict__ row_off,
    const unsigned int* __restrict__ csr, unsigned short* __restrict__ Ob, int N) {
    constexpr int TPN = D / 8;
    constexpr int NPB = 256 / TPN;
    int n = blockIdx.x * NPB + threadIdx.x / TPN;
    int d8 = threadIdx.x % TPN;
    if (n >= N) return;
    const uint4* Hv = reinterpret_cast<const uint4*>(Hb);

    float acc[8];
    {
        uint4 s = Hv[(size_t)n * TPN + d8];
        acc[0] = bflo(s.x); acc[1] = bfhi(s.x);
        acc[2] = bflo(s.y); acc[3] = bfhi(s.y);
        acc[4] = bflo(s.z); acc[5] = bfhi(s.z);
        acc[6] = bflo(s.w); acc[7] = bfhi(s.w);
    }
    auto madd = [&](uint4 v, float w) {
        acc[0] += bflo(v.x) * w; acc[1] += bfhi(v.x) * w;
        acc[2] += bflo(v.y) * w; acc[3] += bfhi(v.y) * w;
        acc[4] += bflo(v.z) * w; acc[5] += bfhi(v.z) * w;
        acc[6] += bflo(v.w) * w; acc[7] += bfhi(v.w) * w;
    };
    int e = row_off[n];
    int e1 = row_off[n + 1];
    for (; e + 4 <= e1; e += 4) {
        unsigned int c0 = csr[e], c1 = csr[e + 1], c2 = csr[e + 2], c3 = csr[e + 3];
        uint4 v0 = Hv[(size_t)(c0 & 0xFFFFu) * TPN + d8];
        uint4 v1 = Hv[(size_t)(c1 & 0xFFFFu) * TPN + d8];
        uint4 v2 = Hv[(size_t)(c2 & 0xFFFFu) * TPN + d8];
        uint4 v3 = Hv[(size_t)(c3 & 0xFFFFu) * TPN + d8];
        madd(v0, bfhi(c0));
        madd(v1, bfhi(c1));
        madd(v2, bfhi(c2));
        madd(v3, bfhi(c3));
    }
    for (; e < e1; ++e) {
        unsigned int c = csr[e];
        madd(Hv[(size_t)(c & 0xFFFFu) * TPN + d8], bfhi(c));
    }
    uint4 o;
    o.x = (unsigned int)f2bf(acc[0]) | ((unsigned int)f2bf(acc[1]) << 16);
    o.y = (unsigned int)f2bf(acc[2]) | ((unsigned int)f2bf(acc[3]) << 16);
    o.z = (unsigned int)f2bf(acc[4]) | ((unsigned int)f2bf(acc[5]) << 16);
    o.w = (unsigned int)f2bf(acc[6]) | ((unsigned int)f2bf(acc[7]) << 16);
    reinterpret_cast<uint4*>(Ob)[(size_t)n * TPN + d8] = o;
}

// ---------------- Pool ----------------

// input: bf16 [N][64]. 16 row-lanes x 16 col-lanes (4 bf16 each).
__global__ __launch_bounds__(256) void pool_kernel(const unsigned short* __restrict__ Hb,
                                                   const int* __restrict__ batch,
                                                   float* __restrict__ sums, int N,
                                                   int rows_per_blk) {
    __shared__ float bins[16 * 64];
    int tid = threadIdx.x;
    for (int i = tid; i < 1024; i += 256) bins[i] = 0.f;
    __syncthreads();
    int d4 = tid & 15;
    int rl = tid >> 4;
    int n0 = blockIdx.x * rows_per_blk;
    int n1 = min(n0 + rows_per_blk, N);
    const uint2* Hv = reinterpret_cast<const uint2*>(Hb);   // 4 bf16 per uint2
    float r0 = 0.f, r1 = 0.f, r2 = 0.f, r3 = 0.f;
    int cur = -1;
    for (int n = n0 + rl; n < n1; n += 16) {
        int b = batch[n];
        if (b != cur) {
            if (cur >= 0) {
                atomicAdd(&bins[cur * 64 + d4 * 4 + 0], r0);
                atomicAdd(&bins[cur * 64 + d4 * 4 + 1], r1);
                atomicAdd(&bins[cur * 64 + d4 * 4 + 2], r2);
                atomicAdd(&bins[cur * 64 + d4 * 4 + 3], r3);
            }
            cur = b;
            r0 = r1 = r2 = r3 = 0.f;
        }
        uint2 v = Hv[(size_t)n * 16 + d4];
        r0 += bflo(v.x); r1 += bfhi(v.x); r2 += bflo(v.y); r3 += bfhi(v.y);
    }
    if (cur >= 0) {
        atomicAdd(&bins[cur * 64 + d4 * 4 + 0], r0);
        atomicAdd(&bins[cur * 64 + d4 * 4 + 1], r1);
        atomicAdd(&bins[cur * 64 + d4 * 4 + 2], r2);
        atomicAdd(&bins[cur * 64 + d4 * 4 + 3], r3);
    }
    __syncthreads();
    for (int i = tid; i < 1024; i += 256) {
        float v = bins[i];
        if (v != 0.f) atomicAdd(&sums[i], v);
    }
}

// finalize with inline per-graph counts (batch sorted -> binary search; wave-uniform g)
__global__ void finalize_kernel(const float* __restrict__ sums, const int* __restrict__ batch,
                                int N, float* __restrict__ out) {
    int i = blockIdx.x * blockDim.x + threadIdx.x;
    if (i >= 1024) return;
    int g = i >> 6;
    auto lower_bound = [&](int key) {
        int lo = 0, hi = N;
        while (lo < hi) { int mid = (lo + hi) >> 1; if (batch[mid] < key) lo = mid + 1; else hi = mid; }
        return lo;
    };
    int c = lower_bound(g + 1) - lower_bound(g);
    out[i] = sums[i] / (float)max(c, 1);
}

// ---------------- launch ----------------

extern "C" void kernel_launch(void* const* d_in, const int* in_sizes, int n_in,
                              void* d_out, int out_size, void* d_ws, size_t ws_size,
                              hipStream_t stream) {
    const float* x   = (const float*)d_in[0];
    const int*   ei  = (const int*)d_in[1];
    const float* ea  = (const float*)d_in[2];
    const int*   bat = (const int*)d_in[3];
    const float* W1  = (const float*)d_in[4];
    const float* b1  = (const float*)d_in[5];
    const float* W2  = (const float*)d_in[6];
    const float* b2  = (const float*)d_in[7];
    const float* W3  = (const float*)d_in[8];
    const float* b3  = (const float*)d_in[9];

    const int N = in_sizes[0] / 128;
    const int E = in_sizes[2];
    const int* src = ei;
    const int* dst = ei + E;

    auto align = [](size_t v) { return (v + 255) & ~(size_t)255; };
    char* p = (char*)d_ws;
    unsigned short* Xb   = (unsigned short*)p; p += align((size_t)N * 128 * 2);
    unsigned short* Hb   = (unsigned short*)p; p += align((size_t)N * 128 * 2);
    unsigned short* Ab   = (unsigned short*)p; p += align((size_t)N * 128 * 2);
    unsigned short* Ab3  = (unsigned short*)p; p += align((size_t)N * 64 * 2);
    unsigned short* Wt1  = (unsigned short*)p; p += align(128 * 128 * 2);
    unsigned short* Wt2  = (unsigned short*)p; p += align(128 * 128 * 2);
    unsigned short* Wt3  = (unsigned short*)p; p += align(64 * 128 * 2);
    int*   deg      = (int*)p;   p += align((size_t)N * sizeof(int));
    int*   row_off  = (int*)p;   p += align((size_t)(N + 1) * sizeof(int));
    int*   cursor   = (int*)p;   p += align((size_t)N * sizeof(int));
    unsigned int* csr = (unsigned int*)p; p += align((size_t)E * sizeof(unsigned int));
    int*   blk_sums = (int*)p;   p += align(128 * sizeof(int));
    float* sums     = (float*)p; p += align(1024 * sizeof(float));

    hipMemsetAsync(deg, 0, (size_t)N * sizeof(int), stream);
    hipMemsetAsync(sums, 0, 1024 * sizeof(float), stream);

    int eb = (E + 255) / 256;
    int nb = (N + 1023) / 1024;

    // fused prep: x->bf16 (xblocks), hist (eb), W-prep (20 blocks)
    int n4 = N * 128 / 4;
    int xblocks = (n4 + 255) / 256;
    prep_kernel<<<xblocks + eb + 20, 256, 0, stream>>>(
        x, Xb, n4, xblocks, dst, deg, E, eb, W1, Wt1, W2, Wt2, W3, Wt3);

    scan1_kernel<<<nb, 1024, 0, stream>>>(deg, row_off, blk_sums, N);
    scan2_kernel<<<1, 128, 0, stream>>>(blk_sums, nb);
    scan3_kernel<<<nb, 1024, 0, stream>>>(row_off, blk_sums, cursor, N, E);
    build_csr_kernel<<<eb, 256, 0, stream>>>(src, dst, ea, cursor, csr, E);

    int gb = (N + 63) / 64;
    // layer 1
    gemm_mfma_kernel<128><<<gb, 256, 0, stream>>>(Xb, Wt1, b1, Hb, N);
    aggregate_bf16_kernel<128><<<(N + 15) / 16, 256, 0, stream>>>(Hb, row_off, csr, Ab, N);
    // layer 2
    gemm_mfma_kernel<128><<<gb, 256, 0, stream>>>(Ab, Wt2, b2, Hb, N);
    aggregate_bf16_kernel<128><<<(N + 15) / 16, 256, 0, stream>>>(Hb, row_off, csr, Ab, N);
    // layer 3 (DOUT = 64)
    gemm_mfma_kernel<64><<<gb, 256, 0, stream>>>(Ab, Wt3, b3, Hb, N);
    aggregate_bf16_kernel<64><<<(N + 31) / 32, 256, 0, stream>>>(Hb, row_off, csr, Ab3, N);

    // pool
    int pool_blocks = 512;
    int rows_per_blk = (N + pool_blocks - 1) / pool_blocks;
    pool_kernel<<<pool_blocks, 256, 0, stream>>>(Ab3, bat, sums, N, rows_per_blk);
    finalize_kernel<<<4, 256, 0, stream>>>(sums, bat, N, (float*)d_out);
}